// Round 1
// baseline (619.469 us; speedup 1.0000x reference)
//
#include <hip/hip_runtime.h>
#include <hip/hip_bf16.h>

typedef short short8 __attribute__((ext_vector_type(8)));
typedef float f32x4 __attribute__((ext_vector_type(4)));

#define MFMA16(a, b, c) __builtin_amdgcn_mfma_f32_16x16x32_bf16((a), (b), (c), 0, 0, 0)

__device__ __forceinline__ unsigned short f2b(float x) {
    // RNE fp32 -> bf16 (values are finite; NaN path not needed)
    unsigned int u = __float_as_uint(x);
    unsigned int r = u + 0x7FFFu + ((u >> 16) & 1u);
    return (unsigned short)(r >> 16);
}

// ---------------------------------------------------------------- casts
__global__ __launch_bounds__(256) void cast4_kernel(const float* __restrict__ in,
                                                    unsigned short* __restrict__ out,
                                                    int n4) {
    int i = blockIdx.x * 256 + threadIdx.x;
    if (i < n4) {
        float4 v = ((const float4*)in)[i];
        ushort4 o;
        o.x = f2b(v.x); o.y = f2b(v.y); o.z = f2b(v.z); o.w = f2b(v.w);
        ((ushort4*)out)[i] = o;
    }
}

// in: K x N fp32 row-major; out: N x K bf16 row-major (i.e. transposed)
__global__ __launch_bounds__(256) void cast_transpose_kernel(const float* __restrict__ in,
                                                             unsigned short* __restrict__ out,
                                                             int K, int N) {
    int idx = blockIdx.x * 256 + threadIdx.x;
    if (idx < K * N) {
        int k = idx / N;
        int n = idx - k * N;
        out[(size_t)n * K + k] = f2b(in[idx]);
    }
}

// ---------------------------------------------------------------- GEMM
// C[M][N] = A[M][K] * Bt[N][K]^T   (A, Bt bf16 row-major; fp32 accumulate)
// 128x128 block tile, 4 waves in 2x2, each wave 64x64 via 4x4 MFMA 16x16x32.
template <bool WRITE_BF16>
__global__ __launch_bounds__(256) void gemm_nt(const unsigned short* __restrict__ A,
                                               const unsigned short* __restrict__ Bt,
                                               void* __restrict__ C,
                                               int M, int N, int K) {
    const int PITCH = 40; // 32 + 8 pad (80B rows: 16B-aligned, 2-way bank alias = free)
    __shared__ unsigned short As[128 * PITCH];
    __shared__ unsigned short Bs[128 * PITCH];

    const int tid  = threadIdx.x;
    const int wave = tid >> 6;
    const int lane = tid & 63;
    const int l16  = lane & 15;
    const int quad = lane >> 4;
    const int m0 = blockIdx.y * 128;
    const int n0 = blockIdx.x * 128;
    const int wm = (wave >> 1) * 64;
    const int wn = (wave & 1) * 64;

    // staging: 512 chunks of 8 bf16 per operand; thread t does chunks t and t+256
    const int r0  = tid >> 2;
    const int kc8 = (tid & 3) * 8;

    f32x4 acc[4][4] = {};

    for (int k0 = 0; k0 < K; k0 += 32) {
        short8 av0 = *(const short8*)(A  + (size_t)(m0 + r0)      * K + k0 + kc8);
        short8 av1 = *(const short8*)(A  + (size_t)(m0 + r0 + 64) * K + k0 + kc8);
        short8 bv0 = *(const short8*)(Bt + (size_t)(n0 + r0)      * K + k0 + kc8);
        short8 bv1 = *(const short8*)(Bt + (size_t)(n0 + r0 + 64) * K + k0 + kc8);
        __syncthreads(); // previous iteration's readers done
        *(short8*)(As + r0 * PITCH + kc8)        = av0;
        *(short8*)(As + (r0 + 64) * PITCH + kc8) = av1;
        *(short8*)(Bs + r0 * PITCH + kc8)        = bv0;
        *(short8*)(Bs + (r0 + 64) * PITCH + kc8) = bv1;
        __syncthreads();

        short8 af[4], bf[4];
#pragma unroll
        for (int i = 0; i < 4; i++) {
            af[i] = *(const short8*)(As + (wm + i * 16 + l16) * PITCH + quad * 8);
            bf[i] = *(const short8*)(Bs + (wn + i * 16 + l16) * PITCH + quad * 8);
        }
#pragma unroll
        for (int i = 0; i < 4; i++)
#pragma unroll
            for (int j = 0; j < 4; j++)
                acc[i][j] = MFMA16(af[i], bf[j], acc[i][j]);
    }

#pragma unroll
    for (int i = 0; i < 4; i++) {
#pragma unroll
        for (int j = 0; j < 4; j++) {
#pragma unroll
            for (int r = 0; r < 4; r++) {
                int row = m0 + wm + i * 16 + quad * 4 + r;
                int col = n0 + wn + j * 16 + l16;
                float v = acc[i][j][r];
                if (WRITE_BF16)
                    ((unsigned short*)C)[(size_t)row * N + col] = f2b(v);
                else
                    ((float*)C)[(size_t)row * N + col] = v;
            }
        }
    }
}

// ---------------------------------------------------------------- flash attention
// qkv: (B*T) x 3072 bf16 rows = [Q(1024) | K(1024) | V(1024)], head h at cols h*64.
// attn out: (B*T) x 1024 bf16, col h*64 + d.
// Block: 64 q-rows (4 waves x 16), loop k-tiles of 32, causal.
__global__ __launch_bounds__(256) void attention_kernel(const unsigned short* __restrict__ qkv,
                                                        unsigned short* __restrict__ attn) {
    const int T = 2048, E = 3072;
    const int b = blockIdx.z, h = blockIdx.y;
    const int qb0 = blockIdx.x * 64;
    const int tid = threadIdx.x, wave = tid >> 6, lane = tid & 63;
    const int l16 = lane & 15, quad = lane >> 4;

    const unsigned short* Qp = qkv + (size_t)b * T * E + h * 64;
    const unsigned short* Kp = Qp + 1024;
    const unsigned short* Vp = Qp + 2048;

    const int KP = 72;  // Ks pitch (144B rows: 16B-aligned)
    const int VP = 48;  // Vts pitch (96B rows: 16B-aligned)
    __shared__ unsigned short Ks[32 * 72];   // [t_kk][d]
    __shared__ unsigned short Vts[64 * 48];  // [d][t_kk] (transposed)
    __shared__ unsigned short Ps[4][16 * 32];

    const int qw0 = qb0 + wave * 16;

    // Q fragments (reused across all k-tiles): A-operand layout
    short8 qf0 = *(const short8*)(Qp + (size_t)(qw0 + l16) * E + quad * 8);
    short8 qf1 = *(const short8*)(Qp + (size_t)(qw0 + l16) * E + 32 + quad * 8);

    f32x4 o[4] = {};
    float m_i[4], l_i[4];
#pragma unroll
    for (int r = 0; r < 4; r++) { m_i[r] = -1e30f; l_i[r] = 0.f; }

    // staging mapping: 256 threads cover 32 rows x 8 chunks of 8
    const int srow = tid >> 3;
    const int sdc  = (tid & 7) * 8;

    const int nkt = qb0 / 32 + 2;
    for (int kt = 0; kt < nkt; kt++) {
        const int tk0 = kt * 32;
        short8 kv = *(const short8*)(Kp + (size_t)(tk0 + srow) * E + sdc);
        short8 vv = *(const short8*)(Vp + (size_t)(tk0 + srow) * E + sdc);
        __syncthreads();
        *(short8*)(Ks + srow * KP + sdc) = kv;
#pragma unroll
        for (int j = 0; j < 8; j++)
            Vts[(sdc + j) * VP + srow] = ((const unsigned short*)&vv)[j];
        __syncthreads();

        if (tk0 <= qw0 + 15) { // wave-uniform
            f32x4 s[2] = {};
#pragma unroll
            for (int nn = 0; nn < 2; nn++) {
                short8 kf0 = *(const short8*)(Ks + (nn * 16 + l16) * KP + quad * 8);
                short8 kf1 = *(const short8*)(Ks + (nn * 16 + l16) * KP + 32 + quad * 8);
                s[nn] = MFMA16(qf0, kf0, s[nn]);
                s[nn] = MFMA16(qf1, kf1, s[nn]);
            }
#pragma unroll
            for (int r = 0; r < 4; r++) {
                const int qg = qw0 + quad * 4 + r;
                float v0 = s[0][r] * 0.125f;
                float v1 = s[1][r] * 0.125f;
                if (tk0 + l16 > qg)      v0 = -1e30f;
                if (tk0 + 16 + l16 > qg) v1 = -1e30f;
                float mx = fmaxf(v0, v1);
                mx = fmaxf(mx, __shfl_xor(mx, 1));
                mx = fmaxf(mx, __shfl_xor(mx, 2));
                mx = fmaxf(mx, __shfl_xor(mx, 4));
                mx = fmaxf(mx, __shfl_xor(mx, 8));
                float mnew  = fmaxf(m_i[r], mx);
                float alpha = exp2f((m_i[r] - mnew) * 1.44269504f);
                float p0 = exp2f((v0 - mnew) * 1.44269504f);
                float p1 = exp2f((v1 - mnew) * 1.44269504f);
                float rs = p0 + p1;
                rs += __shfl_xor(rs, 1);
                rs += __shfl_xor(rs, 2);
                rs += __shfl_xor(rs, 4);
                rs += __shfl_xor(rs, 8);
                l_i[r] = l_i[r] * alpha + rs;
                m_i[r] = mnew;
                o[0][r] *= alpha; o[1][r] *= alpha; o[2][r] *= alpha; o[3][r] *= alpha;
                Ps[wave][(quad * 4 + r) * 32 + l16]      = f2b(p0);
                Ps[wave][(quad * 4 + r) * 32 + 16 + l16] = f2b(p1);
            }
            // P in A-operand layout (LDS round-trip; wave-internal, compiler inserts lgkmcnt)
            short8 pf = *(const short8*)(&Ps[wave][l16 * 32 + quad * 8]);
#pragma unroll
            for (int n = 0; n < 4; n++) {
                short8 vf = *(const short8*)(Vts + (n * 16 + l16) * VP + quad * 8);
                o[n] = MFMA16(pf, vf, o[n]);
            }
        }
    }

#pragma unroll
    for (int n = 0; n < 4; n++)
#pragma unroll
        for (int r = 0; r < 4; r++) {
            float v = o[n][r] / l_i[r];
            int row = qw0 + quad * 4 + r;
            attn[(size_t)(b * T + row) * 1024 + h * 64 + n * 16 + l16] = f2b(v);
        }
}

// ---------------------------------------------------------------- launch
extern "C" void kernel_launch(void* const* d_in, const int* in_sizes, int n_in,
                              void* d_out, int out_size, void* d_ws, size_t ws_size,
                              hipStream_t stream) {
    const float* x     = (const float*)d_in[0]; // (4,2048,1024)
    const float* w_qkv = (const float*)d_in[1]; // (1024,3072)
    const float* w_out = (const float*)d_in[2]; // (1024,1024)
    float* out = (float*)d_out;                 // (4,2048,1024) fp32

    const int M = 8192, D = 1024, E = 3072;

    char* ws = (char*)d_ws;
    unsigned short* xb    = (unsigned short*)ws;                          // 16 MB (reused as attn buf)
    unsigned short* wqkvT = (unsigned short*)(ws + (size_t)16777216);     // 6 MB
    unsigned short* woutT = (unsigned short*)(ws + (size_t)23068672);     // 2 MB
    unsigned short* qkvb  = (unsigned short*)(ws + (size_t)25165824);     // 48 MB
    unsigned short* attnb = xb;

    cast4_kernel<<<(M * D / 4 + 255) / 256, 256, 0, stream>>>(x, xb, M * D / 4);
    cast_transpose_kernel<<<(D * E + 255) / 256, 256, 0, stream>>>(w_qkv, wqkvT, D, E);
    cast_transpose_kernel<<<(D * D + 255) / 256, 256, 0, stream>>>(w_out, woutT, D, D);

    gemm_nt<true><<<dim3(E / 128, M / 128), 256, 0, stream>>>(xb, wqkvT, qkvb, M, E, D);

    attention_kernel<<<dim3(2048 / 64, 16, 4), 256, 0, stream>>>(qkvb, attnb);

    gemm_nt<false><<<dim3(D / 128, M / 128), 256, 0, stream>>>(attnb, woutT, out, M, D, D);
}

// Round 2
// 336.256 us; speedup vs baseline: 1.8423x; 1.8423x over previous
//
#include <hip/hip_runtime.h>
#include <hip/hip_bf16.h>

typedef short short8 __attribute__((ext_vector_type(8)));
typedef float f32x4 __attribute__((ext_vector_type(4)));

#define MFMA16(a, b, c) __builtin_amdgcn_mfma_f32_16x16x32_bf16((a), (b), (c), 0, 0, 0)

__device__ __forceinline__ unsigned short f2b(float x) {
    unsigned int u = __float_as_uint(x);
    unsigned int r = u + 0x7FFFu + ((u >> 16) & 1u);
    return (unsigned short)(r >> 16);
}
__device__ __forceinline__ unsigned pack2(float a, float b) {
    return (unsigned)f2b(a) | ((unsigned)f2b(b) << 16);
}

// ---------------------------------------------------------------- x -> bf16
__global__ __launch_bounds__(256) void cast4_kernel(const float* __restrict__ in,
                                                    unsigned short* __restrict__ out,
                                                    int n4) {
    int i = blockIdx.x * 256 + threadIdx.x;
    if (i < n4) {
        float4 v = ((const float4*)in)[i];
        ushort4 o;
        o.x = f2b(v.x); o.y = f2b(v.y); o.z = f2b(v.z); o.w = f2b(v.w);
        ((ushort4*)out)[i] = o;
    }
}

// ---------------------------------------------------------------- weights: f32 KxN -> bf16 NxK (LDS-tiled)
__global__ __launch_bounds__(256) void transpose_cast_f32(const float* __restrict__ in,
                                                          unsigned short* __restrict__ out,
                                                          int K, int N) {
    __shared__ unsigned short Ls[64 * 66]; // pitch 66: odd-dword pitch breaks bank aliasing
    const int k0 = blockIdx.y * 64, n0 = blockIdx.x * 64;
    const int tid = threadIdx.x;
    const int krow = tid >> 4, nc4 = (tid & 15) * 4;
#pragma unroll
    for (int p = 0; p < 4; p++) {
        float4 v = *(const float4*)(in + (size_t)(k0 + krow + p * 16) * N + n0 + nc4);
        unsigned* d32 = (unsigned*)(Ls + (krow + p * 16) * 66 + nc4);
        d32[0] = pack2(v.x, v.y);
        d32[1] = pack2(v.z, v.w);
    }
    __syncthreads();
    const int n = tid >> 3, kc = (tid & 7) * 8;
#pragma unroll
    for (int p = 0; p < 2; p++) {
        int nn = n + p * 32;
        unsigned short w[8];
#pragma unroll
        for (int j = 0; j < 8; j++) w[j] = Ls[(kc + j) * 66 + nn];
        *(short8*)(out + (size_t)(n0 + nn) * K + k0 + kc) = *(short8*)w;
    }
}

// ---------------------------------------------------------------- V block of qkv -> Vt[b][h][d][t] (bf16)
__global__ __launch_bounds__(256) void vt_transpose(const unsigned short* __restrict__ qkv,
                                                    unsigned short* __restrict__ Vt) {
    const int T = 2048, E = 3072;
    __shared__ unsigned short Ls[64 * 66];
    const int b = blockIdx.z, h = blockIdx.y, t0 = blockIdx.x * 64;
    const int tid = threadIdx.x;
    const int trow = tid >> 3, dc = (tid & 7) * 8;
    const unsigned short* src = qkv + (size_t)(b * T + t0) * E + 2048 + h * 64;
#pragma unroll
    for (int p = 0; p < 2; p++) {
        short8 v = *(const short8*)(src + (size_t)(trow + p * 32) * E + dc);
        unsigned tmp[4];
        *(short8*)tmp = v;
        unsigned* d32 = (unsigned*)(Ls + (trow + p * 32) * 66 + dc);
        d32[0] = tmp[0]; d32[1] = tmp[1]; d32[2] = tmp[2]; d32[3] = tmp[3];
    }
    __syncthreads();
    const int d = tid >> 3, tc = (tid & 7) * 8;
    const size_t obase = ((size_t)(b * 16 + h) * 64) * 2048;
#pragma unroll
    for (int p = 0; p < 2; p++) {
        int dd = d + p * 32;
        unsigned short w[8];
#pragma unroll
        for (int j = 0; j < 8; j++) w[j] = Ls[(tc + j) * 66 + dd];
        *(short8*)(Vt + obase + (size_t)dd * 2048 + t0 + tc) = *(short8*)w;
    }
}

// ---------------------------------------------------------------- GEMM (round-1 proven structure + lda)
// C[M][N] = A[M][K] * Bt[N][K]^T  (A rows stride lda; Bt tight NxK; fp32 acc)
template <bool WRITE_BF16>
__global__ __launch_bounds__(256) void gemm_nt(const unsigned short* __restrict__ A,
                                               const unsigned short* __restrict__ Bt,
                                               void* __restrict__ C,
                                               int M, int N, int K, int lda) {
    const int PITCH = 40;
    __shared__ unsigned short As[128 * PITCH];
    __shared__ unsigned short Bs[128 * PITCH];

    const int tid  = threadIdx.x;
    const int wave = tid >> 6;
    const int lane = tid & 63;
    const int l16  = lane & 15;
    const int quad = lane >> 4;
    const int m0 = blockIdx.y * 128;
    const int n0 = blockIdx.x * 128;
    const int wm = (wave >> 1) * 64;
    const int wn = (wave & 1) * 64;

    const int r0  = tid >> 2;
    const int kc8 = (tid & 3) * 8;

    f32x4 acc[4][4] = {};

    for (int k0 = 0; k0 < K; k0 += 32) {
        short8 av0 = *(const short8*)(A  + (size_t)(m0 + r0)      * lda + k0 + kc8);
        short8 av1 = *(const short8*)(A  + (size_t)(m0 + r0 + 64) * lda + k0 + kc8);
        short8 bv0 = *(const short8*)(Bt + (size_t)(n0 + r0)      * K + k0 + kc8);
        short8 bv1 = *(const short8*)(Bt + (size_t)(n0 + r0 + 64) * K + k0 + kc8);
        __syncthreads();
        *(short8*)(As + r0 * PITCH + kc8)        = av0;
        *(short8*)(As + (r0 + 64) * PITCH + kc8) = av1;
        *(short8*)(Bs + r0 * PITCH + kc8)        = bv0;
        *(short8*)(Bs + (r0 + 64) * PITCH + kc8) = bv1;
        __syncthreads();

        short8 af[4], bf[4];
#pragma unroll
        for (int i = 0; i < 4; i++) {
            af[i] = *(const short8*)(As + (wm + i * 16 + l16) * PITCH + quad * 8);
            bf[i] = *(const short8*)(Bs + (wn + i * 16 + l16) * PITCH + quad * 8);
        }
#pragma unroll
        for (int i = 0; i < 4; i++)
#pragma unroll
            for (int j = 0; j < 4; j++)
                acc[i][j] = MFMA16(af[i], bf[j], acc[i][j]);
    }

#pragma unroll
    for (int i = 0; i < 4; i++)
#pragma unroll
        for (int j = 0; j < 4; j++)
#pragma unroll
            for (int r = 0; r < 4; r++) {
                int row = m0 + wm + i * 16 + quad * 4 + r;
                int col = n0 + wn + j * 16 + l16;
                float v = acc[i][j][r];
                if (WRITE_BF16)
                    ((unsigned short*)C)[(size_t)row * N + col] = f2b(v);
                else
                    ((float*)C)[(size_t)row * N + col] = v;
            }
}

// ---------------------------------------------------------------- flash attention, S^T formulation
// S^T = K.Q^T (C-layout: row=t, col=q) -> per-lane softmax (fixed max, no shuffles)
// O^T = V^T.P^T (A=V^T from pre-transposed global, B=P via wave-private LDS round-trip)
__global__ __launch_bounds__(256) void attention_kernel(const unsigned short* qkv,
                                                        const unsigned short* Vt,
                                                        unsigned short* attn) {
    const int T = 2048, E = 3072;
    const int b = blockIdx.z, h = blockIdx.y, qb0 = blockIdx.x * 128;
    const int tid = threadIdx.x, wave = tid >> 6, lane = tid & 63;
    const int l16 = lane & 15, quad = lane >> 4;
    const int qw0 = qb0 + wave * 32;

    const unsigned short* Qp  = qkv + (size_t)b * T * E + h * 64;
    const unsigned short* Kp  = Qp + 1024;
    const unsigned short* Vbh = Vt + ((size_t)(b * 16 + h) * 64) * 2048;

    __shared__ unsigned short Ks[64 * 72];   // [t][d]
    __shared__ unsigned short Vts[64 * 72];  // [d][t]
    __shared__ unsigned short Ps[4][32 * 40]; // per-wave [q_local][t_half_local]
    unsigned short* Psw = Ps[wave];

    // Q B-frags (persistent): B[n=q][k=d]
    short8 qf[2][2];
#pragma unroll
    for (int nt = 0; nt < 2; nt++)
#pragma unroll
        for (int kd = 0; kd < 2; kd++)
            qf[nt][kd] = *(const short8*)(Qp + (size_t)(qw0 + nt * 16 + l16) * E + kd * 32 + quad * 8);

    f32x4 o[4][2] = {};          // [dt][nt]: O^T[d][q]
    float l_acc[2] = {0.f, 0.f};

    const int srow = tid >> 2, sch = (tid & 3) * 8;
    const float C1 = 0.125f * 1.44269504f; // scale * log2(e)

    const int nkt = qb0 / 64 + 2;
    for (int kt = 0; kt < nkt; kt++) {
        const int tk0 = kt * 64;
        short8 kv0 = *(const short8*)(Kp + (size_t)(tk0 + srow) * E + sch);
        short8 kv1 = *(const short8*)(Kp + (size_t)(tk0 + srow) * E + 32 + sch);
        short8 vv0 = *(const short8*)(Vbh + (size_t)srow * T + tk0 + sch);
        short8 vv1 = *(const short8*)(Vbh + (size_t)srow * T + tk0 + 32 + sch);
        __syncthreads();
        *(short8*)(Ks + srow * 72 + sch)       = kv0;
        *(short8*)(Ks + srow * 72 + 32 + sch)  = kv1;
        *(short8*)(Vts + srow * 72 + sch)      = vv0;
        *(short8*)(Vts + srow * 72 + 32 + sch) = vv1;
        __syncthreads();

#pragma unroll
        for (int th = 0; th < 2; th++) {
            if (tk0 + th * 32 > qw0 + 31) continue; // whole half beyond this wave's queries

            // ---- S^T tiles for this t-half
            f32x4 s[2][2] = {}; // [nt][mi]
#pragma unroll
            for (int mi = 0; mi < 2; mi++) {
                const int mt = th * 2 + mi;
                short8 kf0 = *(const short8*)(Ks + (mt * 16 + l16) * 72 + quad * 8);
                short8 kf1 = *(const short8*)(Ks + (mt * 16 + l16) * 72 + 32 + quad * 8);
#pragma unroll
                for (int nt = 0; nt < 2; nt++)
                    if (tk0 + mt * 16 <= qw0 + nt * 16 + 15) {
                        s[nt][mi] = MFMA16(kf0, qf[nt][0], s[nt][mi]);
                        s[nt][mi] = MFMA16(kf1, qf[nt][1], s[nt][mi]);
                    }
            }
            // ---- softmax (fixed max) + pack + store P (wave-private)
#pragma unroll
            for (int nt = 0; nt < 2; nt++)
#pragma unroll
                for (int mi = 0; mi < 2; mi++) {
                    const int mt = th * 2 + mi;
                    unsigned pk0 = 0, pk1 = 0;
                    if (tk0 + mt * 16 <= qw0 + nt * 16 + 15) {
                        const bool full = (tk0 + mt * 16 + 15) <= (qw0 + nt * 16);
                        float p[4];
#pragma unroll
                        for (int r = 0; r < 4; r++) {
                            float e = __builtin_amdgcn_exp2f(s[nt][mi][r] * C1);
                            if (!full)
                                e = (tk0 + mt * 16 + quad * 4 + r <= qw0 + nt * 16 + l16) ? e : 0.f;
                            p[r] = e;
                        }
                        l_acc[nt] += (p[0] + p[1]) + (p[2] + p[3]);
                        pk0 = pack2(p[0], p[1]);
                        pk1 = pack2(p[2], p[3]);
                    }
                    uint2 pr; pr.x = pk0; pr.y = pk1;
                    *(uint2*)(Psw + (nt * 16 + l16) * 40 + mi * 16 + quad * 4) = pr;
                }
            // ---- O^T += V^T . P^T  (A = V^T frag, B = P row-major frag)
            short8 vf[4];
#pragma unroll
            for (int dt = 0; dt < 4; dt++)
                vf[dt] = *(const short8*)(Vts + (dt * 16 + l16) * 72 + th * 32 + quad * 8);
#pragma unroll
            for (int nt = 0; nt < 2; nt++) {
                if (tk0 + th * 32 > qw0 + nt * 16 + 15) continue;
                short8 pf = *(const short8*)(Psw + (nt * 16 + l16) * 40 + quad * 8);
#pragma unroll
                for (int dt = 0; dt < 4; dt++)
                    o[dt][nt] = MFMA16(vf[dt], pf, o[dt][nt]);
            }
        }
    }

    // ---- epilogue: reduce l over quads, normalize, store (into dead V columns of qkv)
    float rl[2];
#pragma unroll
    for (int nt = 0; nt < 2; nt++) {
        float l = l_acc[nt];
        l += __shfl_xor(l, 16);
        l += __shfl_xor(l, 32);
        rl[nt] = 1.f / l;
    }
#pragma unroll
    for (int nt = 0; nt < 2; nt++) {
        const int q = qw0 + nt * 16 + l16;
#pragma unroll
        for (int dt = 0; dt < 4; dt++) {
            ushort4 wv;
            wv.x = f2b(o[dt][nt][0] * rl[nt]);
            wv.y = f2b(o[dt][nt][1] * rl[nt]);
            wv.z = f2b(o[dt][nt][2] * rl[nt]);
            wv.w = f2b(o[dt][nt][3] * rl[nt]);
            *(ushort4*)(attn + (size_t)(b * T + q) * E + h * 64 + dt * 16 + quad * 4) = wv;
        }
    }
}

// ---------------------------------------------------------------- launch
extern "C" void kernel_launch(void* const* d_in, const int* in_sizes, int n_in,
                              void* d_out, int out_size, void* d_ws, size_t ws_size,
                              hipStream_t stream) {
    const float* x     = (const float*)d_in[0]; // (4,2048,1024)
    const float* w_qkv = (const float*)d_in[1]; // (1024,3072)
    const float* w_out = (const float*)d_in[2]; // (1024,1024)
    float* out = (float*)d_out;

    const int M = 8192, D = 1024, E = 3072;

    char* ws = (char*)d_ws;
    unsigned short* xb    = (unsigned short*)ws;                      // 16 MB; reused as Vt
    unsigned short* wqkvT = (unsigned short*)(ws + (size_t)16777216); // 6 MB
    unsigned short* woutT = (unsigned short*)(ws + (size_t)23068672); // 2 MB
    unsigned short* qkvb  = (unsigned short*)(ws + (size_t)25165824); // 48 MB
    unsigned short* Vt    = xb;

    cast4_kernel<<<M * D / 4 / 256, 256, 0, stream>>>(x, xb, M * D / 4);
    transpose_cast_f32<<<dim3(E / 64, D / 64), 256, 0, stream>>>(w_qkv, wqkvT, D, E);
    transpose_cast_f32<<<dim3(D / 64, D / 64), 256, 0, stream>>>(w_out, woutT, D, D);

    gemm_nt<true><<<dim3(E / 128, M / 128), 256, 0, stream>>>(xb, wqkvT, qkvb, M, E, D, D);

    vt_transpose<<<dim3(32, 16, 4), 256, 0, stream>>>(qkvb, Vt);

    // attention writes into the (now dead) V columns of qkvb: per-row offset 2048
    attention_kernel<<<dim3(16, 16, 4), 256, 0, stream>>>(qkvb, Vt, qkvb + 2048);

    gemm_nt<false><<<dim3(D / 128, M / 128), 256, 0, stream>>>(qkvb + 2048, woutT, out, M, D, D, E);
}

// Round 3
// 293.417 us; speedup vs baseline: 2.1112x; 1.1460x over previous
//
#include <hip/hip_runtime.h>
#include <hip/hip_bf16.h>

typedef short short8 __attribute__((ext_vector_type(8)));
typedef float f32x4 __attribute__((ext_vector_type(4)));

#define MFMA16(a, b, c) __builtin_amdgcn_mfma_f32_16x16x32_bf16((a), (b), (c), 0, 0, 0)

// async global->LDS, 16B per lane; LDS dest = wave-uniform base + lane*16
#define GLOAD16(gp, lp)                                                    \
    __builtin_amdgcn_global_load_lds(                                      \
        (const __attribute__((address_space(1))) unsigned int*)(gp),       \
        (__attribute__((address_space(3))) unsigned int*)(lp), 16, 0, 0)

__device__ __forceinline__ unsigned short f2b(float x) {
    unsigned int u = __float_as_uint(x);
    unsigned int r = u + 0x7FFFu + ((u >> 16) & 1u);
    return (unsigned short)(r >> 16);
}

#if __has_builtin(__builtin_amdgcn_cvt_pk_bf16_f32)
__device__ __forceinline__ unsigned pack2(float a, float b) {
    auto v = __builtin_amdgcn_cvt_pk_bf16_f32(a, b); // v_cvt_pk_bf16_f32 (RNE)
    unsigned u;
    __builtin_memcpy(&u, &v, 4);
    return u;
}
#else
__device__ __forceinline__ unsigned pack2(float a, float b) {
    return (unsigned)f2b(a) | ((unsigned)f2b(b) << 16);
}
#endif

// ---------------------------------------------------------------- x -> bf16
__global__ __launch_bounds__(256) void cast4_kernel(const float* __restrict__ in,
                                                    unsigned short* __restrict__ out,
                                                    int n4) {
    int i = blockIdx.x * 256 + threadIdx.x;
    if (i < n4) {
        float4 v = ((const float4*)in)[i];
        ushort4 o;
        o.x = f2b(v.x); o.y = f2b(v.y); o.z = f2b(v.z); o.w = f2b(v.w);
        ((ushort4*)out)[i] = o;
    }
}

// ---------------------------------------------------------------- weights: f32 KxN -> bf16 NxK (LDS-tiled)
__global__ __launch_bounds__(256) void transpose_cast_f32(const float* __restrict__ in,
                                                          unsigned short* __restrict__ out,
                                                          int K, int N) {
    __shared__ unsigned short Ls[64 * 66];
    const int k0 = blockIdx.y * 64, n0 = blockIdx.x * 64;
    const int tid = threadIdx.x;
    const int krow = tid >> 4, nc4 = (tid & 15) * 4;
#pragma unroll
    for (int p = 0; p < 4; p++) {
        float4 v = *(const float4*)(in + (size_t)(k0 + krow + p * 16) * N + n0 + nc4);
        unsigned* d32 = (unsigned*)(Ls + (krow + p * 16) * 66 + nc4);
        d32[0] = pack2(v.x, v.y);
        d32[1] = pack2(v.z, v.w);
    }
    __syncthreads();
    const int n = tid >> 3, kc = (tid & 7) * 8;
#pragma unroll
    for (int p = 0; p < 2; p++) {
        int nn = n + p * 32;
        unsigned short w[8];
#pragma unroll
        for (int j = 0; j < 8; j++) w[j] = Ls[(kc + j) * 66 + nn];
        *(short8*)(out + (size_t)(n0 + nn) * K + k0 + kc) = *(short8*)w;
    }
}

// ---------------------------------------------------------------- V block of qkv -> Vt[b][h][d][t] (bf16)
__global__ __launch_bounds__(256) void vt_transpose(const unsigned short* __restrict__ qkv,
                                                    unsigned short* __restrict__ Vt) {
    const int T = 2048, E = 3072;
    __shared__ unsigned short Ls[64 * 66];
    const int b = blockIdx.z, h = blockIdx.y, t0 = blockIdx.x * 64;
    const int tid = threadIdx.x;
    const int trow = tid >> 3, dc = (tid & 7) * 8;
    const unsigned short* src = qkv + (size_t)(b * T + t0) * E + 2048 + h * 64;
#pragma unroll
    for (int p = 0; p < 2; p++) {
        short8 v = *(const short8*)(src + (size_t)(trow + p * 32) * E + dc);
        unsigned tmp[4];
        *(short8*)tmp = v;
        unsigned* d32 = (unsigned*)(Ls + (trow + p * 32) * 66 + dc);
        d32[0] = tmp[0]; d32[1] = tmp[1]; d32[2] = tmp[2]; d32[3] = tmp[3];
    }
    __syncthreads();
    const int d = tid >> 3, tc = (tid & 7) * 8;
    const size_t obase = ((size_t)(b * 16 + h) * 64) * 2048;
#pragma unroll
    for (int p = 0; p < 2; p++) {
        int dd = d + p * 32;
        unsigned short w[8];
#pragma unroll
        for (int j = 0; j < 8; j++) w[j] = Ls[(tc + j) * 66 + dd];
        *(short8*)(Vt + obase + (size_t)dd * 2048 + t0 + tc) = *(short8*)w;
    }
}

// ---------------------------------------------------------------- GEMM (m97 structure: global_load_lds, 2-barrier)
// C[M][N] = A[M][K] * Bt[N][K]^T  (A rows stride lda; Bt tight NxK; fp32 acc)
// SCALE_Q: multiply cols<1024 by 0.125*log2(e) (pre-scales Q for exp2-softmax)
template <bool WRITE_BF16, bool SCALE_Q>
__global__ __launch_bounds__(256) void gemm_nt(const unsigned short* __restrict__ A,
                                               const unsigned short* __restrict__ Bt,
                                               void* __restrict__ C,
                                               int M, int N, int K, int lda) {
    __shared__ unsigned short As[128 * 32]; // unpadded: required by global_load_lds lane order
    __shared__ unsigned short Bs[128 * 32];

    const int tid  = threadIdx.x;
    const int wave = tid >> 6;
    const int lane = tid & 63;
    const int l16  = lane & 15;
    const int quad = lane >> 4;
    const int m0 = blockIdx.y * 128;
    const int n0 = blockIdx.x * 128;
    const int wm = (wave >> 1) * 64;
    const int wn = (wave & 1) * 64;

    // staging: chunk c = wave*2+p covers tile rows [c*16, c*16+16); lane -> (row c*16+lane/4, col (lane&3)*8)
    const int srow = lane >> 2;
    const int scol = (lane & 3) * 8;
    const unsigned short* Ag0 = A  + (size_t)(m0 + wave * 32 + srow)      * lda + scol;
    const unsigned short* Ag1 = A  + (size_t)(m0 + wave * 32 + 16 + srow) * lda + scol;
    const unsigned short* Bg0 = Bt + (size_t)(n0 + wave * 32 + srow)      * K + scol;
    const unsigned short* Bg1 = Bt + (size_t)(n0 + wave * 32 + 16 + srow) * K + scol;
    unsigned short* Al0 = As + (wave * 2 + 0) * 512;
    unsigned short* Al1 = As + (wave * 2 + 1) * 512;
    unsigned short* Bl0 = Bs + (wave * 2 + 0) * 512;
    unsigned short* Bl1 = Bs + (wave * 2 + 1) * 512;

    f32x4 acc[4][4] = {};

    for (int k0 = 0; k0 < K; k0 += 32) {
        __syncthreads(); // previous iteration's frag reads done
        GLOAD16(Ag0 + k0, Al0);
        GLOAD16(Ag1 + k0, Al1);
        GLOAD16(Bg0 + k0, Bl0);
        GLOAD16(Bg1 + k0, Bl1);
        __syncthreads(); // vmcnt(0) drain: tile ready

        short8 af[4], bf[4];
#pragma unroll
        for (int i = 0; i < 4; i++) {
            af[i] = *(const short8*)(As + (wm + i * 16 + l16) * 32 + quad * 8);
            bf[i] = *(const short8*)(Bs + (wn + i * 16 + l16) * 32 + quad * 8);
        }
#pragma unroll
        for (int i = 0; i < 4; i++)
#pragma unroll
            for (int j = 0; j < 4; j++)
                acc[i][j] = MFMA16(af[i], bf[j], acc[i][j]);
    }

    const float QSCALE = 0.125f * 1.44269504f;
#pragma unroll
    for (int i = 0; i < 4; i++)
#pragma unroll
        for (int j = 0; j < 4; j++)
#pragma unroll
            for (int r = 0; r < 4; r++) {
                int row = m0 + wm + i * 16 + quad * 4 + r;
                int col = n0 + wn + j * 16 + l16;
                float v = acc[i][j][r];
                if (SCALE_Q && col < 1024) v *= QSCALE;
                if (WRITE_BF16)
                    ((unsigned short*)C)[(size_t)row * N + col] = f2b(v);
                else
                    ((float*)C)[(size_t)row * N + col] = v;
            }
}

// ---------------------------------------------------------------- flash attention, S^T formulation
// Q pre-scaled by 0.125*log2(e) => p = exp2(s) directly.
// Causal load-balance: co-resident blocks {same (x,y), z=0..3} get qb summing to 30.
__global__ __launch_bounds__(256) void attention_kernel(const unsigned short* qkv,
                                                        const unsigned short* Vt,
                                                        unsigned short* attn) {
    const int T = 2048, E = 3072;
    const int b = blockIdx.z, h = blockIdx.y;
    const int qs = blockIdx.x;
    int qq = (b & 2) ? ((qs + 8) & 15) : qs;
    const int qb = (b & 1) ? (15 - qq) : qq;
    const int qb0 = qb * 128;
    const int tid = threadIdx.x, wave = tid >> 6, lane = tid & 63;
    const int l16 = lane & 15, quad = lane >> 4;
    const int qw0 = qb0 + wave * 32;

    const unsigned short* Qp  = qkv + (size_t)b * T * E + h * 64;
    const unsigned short* Kp  = Qp + 1024;
    const unsigned short* Vbh = Vt + ((size_t)(b * 16 + h) * 64) * 2048;

    __shared__ unsigned short Ks[64 * 72];    // [t][d]
    __shared__ unsigned short Vts[64 * 72];   // [d][t]
    __shared__ unsigned short Ps[4][32 * 40]; // per-wave [q_local][t_half_local]
    unsigned short* Psw = Ps[wave];

    // Q B-frags (persistent): B[n=q][k=d]
    short8 qf[2][2];
#pragma unroll
    for (int nt = 0; nt < 2; nt++)
#pragma unroll
        for (int kd = 0; kd < 2; kd++)
            qf[nt][kd] = *(const short8*)(Qp + (size_t)(qw0 + nt * 16 + l16) * E + kd * 32 + quad * 8);

    f32x4 o[4][2] = {};          // [dt][nt]: O^T[d][q]
    float l_acc[2] = {0.f, 0.f};

    const int srow = tid >> 2, sch = (tid & 3) * 8;

    const int nkt = qb0 / 64 + 2;
    for (int kt = 0; kt < nkt; kt++) {
        const int tk0 = kt * 64;
        short8 kv0 = *(const short8*)(Kp + (size_t)(tk0 + srow) * E + sch);
        short8 kv1 = *(const short8*)(Kp + (size_t)(tk0 + srow) * E + 32 + sch);
        short8 vv0 = *(const short8*)(Vbh + (size_t)srow * T + tk0 + sch);
        short8 vv1 = *(const short8*)(Vbh + (size_t)srow * T + tk0 + 32 + sch);
        __syncthreads();
        *(short8*)(Ks + srow * 72 + sch)       = kv0;
        *(short8*)(Ks + srow * 72 + 32 + sch)  = kv1;
        *(short8*)(Vts + srow * 72 + sch)      = vv0;
        *(short8*)(Vts + srow * 72 + 32 + sch) = vv1;
        __syncthreads();

#pragma unroll
        for (int th = 0; th < 2; th++) {
            if (tk0 + th * 32 > qw0 + 31) continue; // wave-uniform skip

            // ---- S^T tiles for this t-half
            f32x4 s[2][2] = {}; // [nt][mi]
#pragma unroll
            for (int mi = 0; mi < 2; mi++) {
                const int mt = th * 2 + mi;
                short8 kf0 = *(const short8*)(Ks + (mt * 16 + l16) * 72 + quad * 8);
                short8 kf1 = *(const short8*)(Ks + (mt * 16 + l16) * 72 + 32 + quad * 8);
#pragma unroll
                for (int nt = 0; nt < 2; nt++)
                    if (tk0 + mt * 16 <= qw0 + nt * 16 + 15) {
                        s[nt][mi] = MFMA16(kf0, qf[nt][0], s[nt][mi]);
                        s[nt][mi] = MFMA16(kf1, qf[nt][1], s[nt][mi]);
                    }
            }
            // ---- softmax (fixed max; Q pre-scaled so p=exp2(s)) + pack + store P
#pragma unroll
            for (int nt = 0; nt < 2; nt++)
#pragma unroll
                for (int mi = 0; mi < 2; mi++) {
                    const int mt = th * 2 + mi;
                    unsigned pk0 = 0, pk1 = 0;
                    if (tk0 + mt * 16 <= qw0 + nt * 16 + 15) {
                        const bool full = (tk0 + mt * 16 + 15) <= (qw0 + nt * 16);
                        float p[4];
#pragma unroll
                        for (int r = 0; r < 4; r++) {
                            float e = __builtin_amdgcn_exp2f(s[nt][mi][r]);
                            if (!full)
                                e = (tk0 + mt * 16 + quad * 4 + r <= qw0 + nt * 16 + l16) ? e : 0.f;
                            p[r] = e;
                        }
                        l_acc[nt] += (p[0] + p[1]) + (p[2] + p[3]);
                        pk0 = pack2(p[0], p[1]);
                        pk1 = pack2(p[2], p[3]);
                    }
                    uint2 pr; pr.x = pk0; pr.y = pk1;
                    *(uint2*)(Psw + (nt * 16 + l16) * 40 + mi * 16 + quad * 4) = pr;
                }
            // ---- O^T += V^T . P^T
            short8 vf[4];
#pragma unroll
            for (int dt = 0; dt < 4; dt++)
                vf[dt] = *(const short8*)(Vts + (dt * 16 + l16) * 72 + th * 32 + quad * 8);
#pragma unroll
            for (int nt = 0; nt < 2; nt++) {
                if (tk0 + th * 32 > qw0 + nt * 16 + 15) continue;
                short8 pf = *(const short8*)(Psw + (nt * 16 + l16) * 40 + quad * 8);
#pragma unroll
                for (int dt = 0; dt < 4; dt++)
                    o[dt][nt] = MFMA16(vf[dt], pf, o[dt][nt]);
            }
        }
    }

    // ---- epilogue: reduce l over quads, normalize, store into dead V columns of qkv
    float rl[2];
#pragma unroll
    for (int nt = 0; nt < 2; nt++) {
        float l = l_acc[nt];
        l += __shfl_xor(l, 16);
        l += __shfl_xor(l, 32);
        rl[nt] = 1.f / l;
    }
#pragma unroll
    for (int nt = 0; nt < 2; nt++) {
        const int q = qw0 + nt * 16 + l16;
#pragma unroll
        for (int dt = 0; dt < 4; dt++) {
            ushort4 wv;
            wv.x = f2b(o[dt][nt][0] * rl[nt]);
            wv.y = f2b(o[dt][nt][1] * rl[nt]);
            wv.z = f2b(o[dt][nt][2] * rl[nt]);
            wv.w = f2b(o[dt][nt][3] * rl[nt]);
            *(ushort4*)(attn + (size_t)(b * T + q) * E + h * 64 + dt * 16 + quad * 4) = wv;
        }
    }
}

// ---------------------------------------------------------------- launch
extern "C" void kernel_launch(void* const* d_in, const int* in_sizes, int n_in,
                              void* d_out, int out_size, void* d_ws, size_t ws_size,
                              hipStream_t stream) {
    const float* x     = (const float*)d_in[0]; // (4,2048,1024)
    const float* w_qkv = (const float*)d_in[1]; // (1024,3072)
    const float* w_out = (const float*)d_in[2]; // (1024,1024)
    float* out = (float*)d_out;

    const int M = 8192, D = 1024, E = 3072;

    char* ws = (char*)d_ws;
    unsigned short* xb    = (unsigned short*)ws;                      // 16 MB; reused as Vt
    unsigned short* wqkvT = (unsigned short*)(ws + (size_t)16777216); // 6 MB
    unsigned short* woutT = (unsigned short*)(ws + (size_t)23068672); // 2 MB
    unsigned short* qkvb  = (unsigned short*)(ws + (size_t)25165824); // 48 MB
    unsigned short* Vt    = xb;

    cast4_kernel<<<M * D / 4 / 256, 256, 0, stream>>>(x, xb, M * D / 4);
    transpose_cast_f32<<<dim3(E / 64, D / 64), 256, 0, stream>>>(w_qkv, wqkvT, D, E);
    transpose_cast_f32<<<dim3(D / 64, D / 64), 256, 0, stream>>>(w_out, woutT, D, D);

    gemm_nt<true, true><<<dim3(E / 128, M / 128), 256, 0, stream>>>(xb, wqkvT, qkvb, M, E, D, D);

    vt_transpose<<<dim3(32, 16, 4), 256, 0, stream>>>(qkvb, Vt);

    attention_kernel<<<dim3(16, 16, 4), 256, 0, stream>>>(qkvb, Vt, qkvb + 2048);

    gemm_nt<false, false><<<dim3(D / 128, M / 128), 256, 0, stream>>>(qkvb + 2048, woutT, out, M, D, D, E);
}

// Round 4
// 283.314 us; speedup vs baseline: 2.1865x; 1.0357x over previous
//
#include <hip/hip_runtime.h>
#include <hip/hip_bf16.h>

typedef short short8 __attribute__((ext_vector_type(8)));
typedef float f32x4 __attribute__((ext_vector_type(4)));

#define MFMA16(a, b, c) __builtin_amdgcn_mfma_f32_16x16x32_bf16((a), (b), (c), 0, 0, 0)

// async global->LDS, 16B per lane; LDS dest = wave-uniform base + lane*16
#define GLOAD16(gp, lp)                                                    \
    __builtin_amdgcn_global_load_lds(                                      \
        (const __attribute__((address_space(1))) unsigned int*)(gp),       \
        (__attribute__((address_space(3))) unsigned int*)(lp), 16, 0, 0)

__device__ __forceinline__ unsigned short f2b(float x) {
    unsigned int u = __float_as_uint(x);
    unsigned int r = u + 0x7FFFu + ((u >> 16) & 1u);
    return (unsigned short)(r >> 16);
}

#if __has_builtin(__builtin_amdgcn_cvt_pk_bf16_f32)
__device__ __forceinline__ unsigned pack2(float a, float b) {
    auto v = __builtin_amdgcn_cvt_pk_bf16_f32(a, b);
    unsigned u;
    __builtin_memcpy(&u, &v, 4);
    return u;
}
#else
__device__ __forceinline__ unsigned pack2(float a, float b) {
    return (unsigned)f2b(a) | ((unsigned)f2b(b) << 16);
}
#endif

// ---------------------------------------------------------------- x -> bf16
__global__ __launch_bounds__(256) void cast4_kernel(const float* __restrict__ in,
                                                    unsigned short* __restrict__ out,
                                                    int n4) {
    int i = blockIdx.x * 256 + threadIdx.x;
    if (i < n4) {
        float4 v = ((const float4*)in)[i];
        ushort4 o;
        o.x = f2b(v.x); o.y = f2b(v.y); o.z = f2b(v.z); o.w = f2b(v.w);
        ((ushort4*)out)[i] = o;
    }
}

// ---------------------------------------------------------------- weights: f32 KxN -> bf16 NxK (LDS-tiled)
__global__ __launch_bounds__(256) void transpose_cast_f32(const float* __restrict__ in,
                                                          unsigned short* __restrict__ out,
                                                          int K, int N) {
    __shared__ unsigned short Ls[64 * 66];
    const int k0 = blockIdx.y * 64, n0 = blockIdx.x * 64;
    const int tid = threadIdx.x;
    const int krow = tid >> 4, nc4 = (tid & 15) * 4;
#pragma unroll
    for (int p = 0; p < 4; p++) {
        float4 v = *(const float4*)(in + (size_t)(k0 + krow + p * 16) * N + n0 + nc4);
        unsigned* d32 = (unsigned*)(Ls + (krow + p * 16) * 66 + nc4);
        d32[0] = pack2(v.x, v.y);
        d32[1] = pack2(v.z, v.w);
    }
    __syncthreads();
    const int n = tid >> 3, kc = (tid & 7) * 8;
#pragma unroll
    for (int p = 0; p < 2; p++) {
        int nn = n + p * 32;
        unsigned short w[8];
#pragma unroll
        for (int j = 0; j < 8; j++) w[j] = Ls[(kc + j) * 66 + nn];
        *(short8*)(out + (size_t)(n0 + nn) * K + k0 + kc) = *(short8*)w;
    }
}

// ---------------------------------------------------------------- V block of qkv -> Vt[b][h][d][t] (bf16)
__global__ __launch_bounds__(256) void vt_transpose(const unsigned short* __restrict__ qkv,
                                                    unsigned short* __restrict__ Vt) {
    const int T = 2048, E = 3072;
    __shared__ unsigned short Ls[64 * 66];
    const int b = blockIdx.z, h = blockIdx.y, t0 = blockIdx.x * 64;
    const int tid = threadIdx.x;
    const int trow = tid >> 3, dc = (tid & 7) * 8;
    const unsigned short* src = qkv + (size_t)(b * T + t0) * E + 2048 + h * 64;
#pragma unroll
    for (int p = 0; p < 2; p++) {
        short8 v = *(const short8*)(src + (size_t)(trow + p * 32) * E + dc);
        unsigned tmp[4];
        *(short8*)tmp = v;
        unsigned* d32 = (unsigned*)(Ls + (trow + p * 32) * 66 + dc);
        d32[0] = tmp[0]; d32[1] = tmp[1]; d32[2] = tmp[2]; d32[3] = tmp[3];
    }
    __syncthreads();
    const int d = tid >> 3, tc = (tid & 7) * 8;
    const size_t obase = ((size_t)(b * 16 + h) * 64) * 2048;
#pragma unroll
    for (int p = 0; p < 2; p++) {
        int dd = d + p * 32;
        unsigned short w[8];
#pragma unroll
        for (int j = 0; j < 8; j++) w[j] = Ls[(tc + j) * 66 + dd];
        *(short8*)(Vt + obase + (size_t)dd * 2048 + t0 + tc) = *(short8*)w;
    }
}

// ---------------------------------------------------------------- GEMM (m97 + XOR-swizzled frag reads)
// C[M][N] = A[M][K] * Bt[N][K]^T; block tile MT x 128, 4 waves 2x2.
// Swizzle: LDS(row, chunk) holds global chunk (chunk ^ ((row>>1)&3)) -> frag reads 2-way banked (free).
template <int MT, bool WRITE_BF16, bool SCALE_Q>
__global__ __launch_bounds__(256) void gemm_nt(const unsigned short* __restrict__ A,
                                               const unsigned short* __restrict__ Bt,
                                               void* __restrict__ C,
                                               int M, int N, int K, int lda) {
    constexpr int MI  = MT / 32;
    constexpr int ACH = MT / 64; // A staging chunks per wave
    __shared__ unsigned short As[MT * 32];
    __shared__ unsigned short Bs[128 * 32];

    const int tid  = threadIdx.x;
    const int wave = tid >> 6;
    const int lane = tid & 63;
    const int l16  = lane & 15;
    const int quad = lane >> 4;
    const int m0 = blockIdx.y * MT;
    const int n0 = blockIdx.x * 128;
    const int wm = (wave >> 1) * (MT / 2);
    const int wn = (wave & 1) * 64;

    const int srow = lane >> 2;
    const int scol = (((lane & 3) ^ ((lane >> 3) & 3)) * 8); // swizzled source chunk
    const int sw8  = ((l16 >> 1) & 3) * 8;                   // frag-read swizzle

    const unsigned short* Ag[ACH]; unsigned short* Al[ACH];
#pragma unroll
    for (int p = 0; p < ACH; p++) {
        Ag[p] = A + (size_t)(m0 + (wave * ACH + p) * 16 + srow) * lda + scol;
        Al[p] = As + (wave * ACH + p) * 512;
    }
    const unsigned short* Bg[2]; unsigned short* Bl[2];
#pragma unroll
    for (int p = 0; p < 2; p++) {
        Bg[p] = Bt + (size_t)(n0 + (wave * 2 + p) * 16 + srow) * K + scol;
        Bl[p] = Bs + (wave * 2 + p) * 512;
    }

    f32x4 acc[MI][4] = {};

    for (int k0 = 0; k0 < K; k0 += 32) {
        __syncthreads();
#pragma unroll
        for (int p = 0; p < ACH; p++) GLOAD16(Ag[p] + k0, Al[p]);
#pragma unroll
        for (int p = 0; p < 2; p++) GLOAD16(Bg[p] + k0, Bl[p]);
        __syncthreads();

        short8 af[MI], bf[4];
#pragma unroll
        for (int i = 0; i < MI; i++)
            af[i] = *(const short8*)(As + (wm + i * 16 + l16) * 32 + (quad * 8 ^ sw8));
#pragma unroll
        for (int j = 0; j < 4; j++)
            bf[j] = *(const short8*)(Bs + (wn + j * 16 + l16) * 32 + (quad * 8 ^ sw8));
#pragma unroll
        for (int i = 0; i < MI; i++)
#pragma unroll
            for (int j = 0; j < 4; j++)
                acc[i][j] = MFMA16(af[i], bf[j], acc[i][j]);
    }

    const float QSCALE = 0.125f * 1.44269504f;
#pragma unroll
    for (int i = 0; i < MI; i++)
#pragma unroll
        for (int j = 0; j < 4; j++)
#pragma unroll
            for (int r = 0; r < 4; r++) {
                int row = m0 + wm + i * 16 + quad * 4 + r;
                int col = n0 + wn + j * 16 + l16;
                float v = acc[i][j][r];
                if (SCALE_Q && col < 1024) v *= QSCALE;
                if (WRITE_BF16)
                    ((unsigned short*)C)[(size_t)row * N + col] = f2b(v);
                else
                    ((float*)C)[(size_t)row * N + col] = v;
            }
}

// ---------------------------------------------------------------- flash attention
// 64-q blocks (4 waves x 16 q), LPT-ordered grid (qb descending), GLOAD16 K/V staging
// into 4 unpadded swizzled 64x32 panels. Q pre-scaled; fixed-max exp2 softmax.
__global__ __launch_bounds__(256) void attention_kernel(const unsigned short* qkv,
                                                        const unsigned short* Vt,
                                                        unsigned short* attn) {
    const int T = 2048, E = 3072;
    const int bi = blockIdx.x;
    const int qb = 31 - (bi >> 6);          // longest work first
    const int hb = bi & 63;
    const int b = hb >> 4, h = hb & 15;
    const int qb0 = qb * 64;
    const int tid = threadIdx.x, wave = tid >> 6, lane = tid & 63;
    const int l16 = lane & 15, quad = lane >> 4;
    const int qw0 = qb0 + wave * 16;

    const unsigned short* Qp  = qkv + (size_t)b * T * E + h * 64;
    const unsigned short* Kp  = Qp + 1024;
    const unsigned short* Vbh = Vt + ((size_t)(b * 16 + h) * 64) * 2048;

    __shared__ unsigned short Ks[2][64 * 32];   // [kd panel][t][32 d] swizzled
    __shared__ unsigned short Vts[2][64 * 32];  // [th panel][d][32 t] swizzled
    __shared__ unsigned short Ps[4][16 * 40];   // per-wave P, padded pitch
    unsigned short* Psw = Ps[wave];

    // Q B-frags (B[n=q][k=d]), from global (no swizzle)
    short8 qf[2];
#pragma unroll
    for (int kd = 0; kd < 2; kd++)
        qf[kd] = *(const short8*)(Qp + (size_t)(qw0 + l16) * E + kd * 32 + quad * 8);

    f32x4 o[4] = {};   // O^T[d-tile][ (d=quad*4+r, q=l16) ]
    float l_acc = 0.f;

    // staging: wave w owns panel w (K0,K1,V0,V1); 4 GLOAD16 chunks of 16 rows each
    const int srow = lane >> 2;
    const int scol = (((lane & 3) ^ ((lane >> 3) & 3)) * 8);
    const int sw8  = ((l16 >> 1) & 3) * 8;
    const size_t ktstep = (wave < 2) ? (size_t)64 * E : (size_t)64;
    const size_t cstep  = (wave < 2) ? (size_t)16 * E : (size_t)16 * T;
    const unsigned short* g0 = (wave < 2)
            ? Kp + (size_t)srow * E + wave * 32 + scol
            : Vbh + (size_t)srow * T + (wave - 2) * 32 + scol;
    unsigned short* l0 = (wave < 2) ? Ks[wave] : Vts[wave - 2];

    for (int kt = 0; kt <= qb; kt++) {
        const int tk0 = kt * 64;
        const unsigned short* g = g0 + (size_t)kt * ktstep;
        __syncthreads();
#pragma unroll
        for (int c = 0; c < 4; c++) GLOAD16(g + c * cstep, l0 + c * 512);
        __syncthreads();

#pragma unroll
        for (int th = 0; th < 2; th++) {
            if (tk0 + th * 32 > qw0 + 15) continue; // wave-uniform

            f32x4 s[2];
            bool act[2];
#pragma unroll
            for (int mi = 0; mi < 2; mi++) {
                const int t0 = tk0 + (th * 2 + mi) * 16;
                act[mi] = (t0 <= qw0 + 15);
                s[mi] = (f32x4){0.f, 0.f, 0.f, 0.f};
                if (act[mi]) {
                    const int row = (th * 2 + mi) * 16 + l16;
                    short8 kf0 = *(const short8*)(Ks[0] + row * 32 + (quad * 8 ^ sw8));
                    short8 kf1 = *(const short8*)(Ks[1] + row * 32 + (quad * 8 ^ sw8));
                    s[mi] = MFMA16(kf0, qf[0], s[mi]);
                    s[mi] = MFMA16(kf1, qf[1], s[mi]);
                }
            }
#pragma unroll
            for (int mi = 0; mi < 2; mi++) {
                const int t0 = tk0 + (th * 2 + mi) * 16;
                unsigned pk0 = 0, pk1 = 0;
                if (act[mi]) {
                    const bool full = (t0 + 15) <= qw0;
                    float p[4];
#pragma unroll
                    for (int r = 0; r < 4; r++) {
                        float e = __builtin_amdgcn_exp2f(s[mi][r]);
                        if (!full)
                            e = (t0 + quad * 4 + r <= qw0 + l16) ? e : 0.f;
                        p[r] = e;
                    }
                    l_acc += (p[0] + p[1]) + (p[2] + p[3]);
                    pk0 = pack2(p[0], p[1]);
                    pk1 = pack2(p[2], p[3]);
                }
                uint2 pr; pr.x = pk0; pr.y = pk1;
                *(uint2*)(Psw + l16 * 40 + mi * 16 + quad * 4) = pr;
            }
            // O^T += V^T . P^T
            short8 pf = *(const short8*)(Psw + l16 * 40 + quad * 8);
#pragma unroll
            for (int dt = 0; dt < 4; dt++) {
                short8 vf = *(const short8*)(Vts[th] + (dt * 16 + l16) * 32 + (quad * 8 ^ sw8));
                o[dt] = MFMA16(vf, pf, o[dt]);
            }
        }
    }

    float l = l_acc;
    l += __shfl_xor(l, 16);
    l += __shfl_xor(l, 32);
    const float rl = 1.f / l;
    const int q = qw0 + l16;
#pragma unroll
    for (int dt = 0; dt < 4; dt++) {
        ushort4 wv;
        wv.x = f2b(o[dt][0] * rl);
        wv.y = f2b(o[dt][1] * rl);
        wv.z = f2b(o[dt][2] * rl);
        wv.w = f2b(o[dt][3] * rl);
        *(ushort4*)(attn + (size_t)(b * T + q) * E + h * 64 + dt * 16 + quad * 4) = wv;
    }
}

// ---------------------------------------------------------------- launch
extern "C" void kernel_launch(void* const* d_in, const int* in_sizes, int n_in,
                              void* d_out, int out_size, void* d_ws, size_t ws_size,
                              hipStream_t stream) {
    const float* x     = (const float*)d_in[0]; // (4,2048,1024)
    const float* w_qkv = (const float*)d_in[1]; // (1024,3072)
    const float* w_out = (const float*)d_in[2]; // (1024,1024)
    float* out = (float*)d_out;

    const int M = 8192, D = 1024, E = 3072;

    char* ws = (char*)d_ws;
    unsigned short* xb    = (unsigned short*)ws;                      // 16 MB; reused as Vt
    unsigned short* wqkvT = (unsigned short*)(ws + (size_t)16777216); // 6 MB
    unsigned short* woutT = (unsigned short*)(ws + (size_t)23068672); // 2 MB
    unsigned short* qkvb  = (unsigned short*)(ws + (size_t)25165824); // 48 MB
    unsigned short* Vt    = xb;

    cast4_kernel<<<M * D / 4 / 256, 256, 0, stream>>>(x, xb, M * D / 4);
    transpose_cast_f32<<<dim3(E / 64, D / 64), 256, 0, stream>>>(w_qkv, wqkvT, D, E);
    transpose_cast_f32<<<dim3(D / 64, D / 64), 256, 0, stream>>>(w_out, woutT, D, D);

    gemm_nt<128, true, true><<<dim3(E / 128, M / 128), 256, 0, stream>>>(xb, wqkvT, qkvb, M, E, D, D);

    vt_transpose<<<dim3(32, 16, 4), 256, 0, stream>>>(qkvb, Vt);

    attention_kernel<<<dim3(2048), 256, 0, stream>>>(qkvb, Vt, qkvb + 2048);

    gemm_nt<64, false, false><<<dim3(D / 128, M / 64), 256, 0, stream>>>(qkvb + 2048, woutT, out, M, D, D, E);
}

// Round 6
// 268.773 us; speedup vs baseline: 2.3048x; 1.0541x over previous
//
#include <hip/hip_runtime.h>
#include <hip/hip_bf16.h>

typedef short short8 __attribute__((ext_vector_type(8)));
typedef float f32x4 __attribute__((ext_vector_type(4)));
typedef float f32x16 __attribute__((ext_vector_type(16)));

#define MFMA16(a, b, c) __builtin_amdgcn_mfma_f32_16x16x32_bf16((a), (b), (c), 0, 0, 0)
#define MFMA32(a, b, c) __builtin_amdgcn_mfma_f32_32x32x16_bf16((a), (b), (c), 0, 0, 0)

// async global->LDS, 16B per lane; LDS dest = wave-uniform base + lane*16
#define GLOAD16(gp, lp)                                                    \
    __builtin_amdgcn_global_load_lds(                                      \
        (const __attribute__((address_space(1))) unsigned int*)(gp),       \
        (__attribute__((address_space(3))) unsigned int*)(lp), 16, 0, 0)

__device__ __forceinline__ unsigned short f2b(float x) {
    unsigned int u = __float_as_uint(x);
    unsigned int r = u + 0x7FFFu + ((u >> 16) & 1u);
    return (unsigned short)(r >> 16);
}

#if __has_builtin(__builtin_amdgcn_cvt_pk_bf16_f32)
__device__ __forceinline__ unsigned pack2(float a, float b) {
    auto v = __builtin_amdgcn_cvt_pk_bf16_f32(a, b);
    unsigned u;
    __builtin_memcpy(&u, &v, 4);
    return u;
}
#else
__device__ __forceinline__ unsigned pack2(float a, float b) {
    return (unsigned)f2b(a) | ((unsigned)f2b(b) << 16);
}
#endif

// ---------------------------------------------------------------- x -> bf16
__global__ __launch_bounds__(256) void cast4_kernel(const float* __restrict__ in,
                                                    unsigned short* __restrict__ out,
                                                    int n4) {
    int i = blockIdx.x * 256 + threadIdx.x;
    if (i < n4) {
        float4 v = ((const float4*)in)[i];
        ushort4 o;
        o.x = f2b(v.x); o.y = f2b(v.y); o.z = f2b(v.z); o.w = f2b(v.w);
        ((ushort4*)out)[i] = o;
    }
}

// ---------------------------------------------------------------- weights: f32 KxN -> bf16 NxK (LDS-tiled)
__global__ __launch_bounds__(256) void transpose_cast_f32(const float* __restrict__ in,
                                                          unsigned short* __restrict__ out,
                                                          int K, int N) {
    __shared__ unsigned short Ls[64 * 66];
    const int k0 = blockIdx.y * 64, n0 = blockIdx.x * 64;
    const int tid = threadIdx.x;
    const int krow = tid >> 4, nc4 = (tid & 15) * 4;
#pragma unroll
    for (int p = 0; p < 4; p++) {
        float4 v = *(const float4*)(in + (size_t)(k0 + krow + p * 16) * N + n0 + nc4);
        unsigned* d32 = (unsigned*)(Ls + (krow + p * 16) * 66 + nc4);
        d32[0] = pack2(v.x, v.y);
        d32[1] = pack2(v.z, v.w);
    }
    __syncthreads();
    const int n = tid >> 3, kc = (tid & 7) * 8;
#pragma unroll
    for (int p = 0; p < 2; p++) {
        int nn = n + p * 32;
        unsigned short w[8];
#pragma unroll
        for (int j = 0; j < 8; j++) w[j] = Ls[(kc + j) * 66 + nn];
        *(short8*)(out + (size_t)(n0 + nn) * K + k0 + kc) = *(short8*)w;
    }
}

// ---------------------------------------------------------------- QKV GEMM (32x32x16 MFMA, fused V transpose)
// A[8192][1024] * wqkvT[3072][1024]^T. Col-blocks route: [0,1024)->Qb (scaled),
// [1024,2048)->Kb, [2048,3072)->Vt[b*16+h][64 d][2048 t] via LDS-bounce transpose.
__global__ __launch_bounds__(256) void gemm_qkv(const unsigned short* __restrict__ A,
                                                const unsigned short* __restrict__ Bt,
                                                unsigned short* __restrict__ Qb,
                                                unsigned short* __restrict__ Kb,
                                                unsigned short* __restrict__ Vt) {
    const int K = 1024, lda = 1024;
    __shared__ unsigned short smem[8192]; // As 4096 | Bs 4096 (reused as 16KB bounce)
    unsigned short* As = smem;
    unsigned short* Bs = smem + 4096;

    const int tid  = threadIdx.x;
    const int wave = tid >> 6;
    const int lane = tid & 63;
    const int l32  = lane & 31;
    const int hi   = lane >> 5;
    const int m0 = blockIdx.y * 128;
    const int n0 = blockIdx.x * 128;
    const int wm = (wave >> 1) * 64;
    const int wn = (wave & 1) * 64;

    const int srow = lane >> 2;
    const int scol = (((lane & 3) ^ ((lane >> 3) & 3)) * 8);
    const int fsw  = ((l32 >> 1) & 3); // frag-read swizzle key

    const unsigned short* Ag0 = A  + (size_t)(m0 + wave * 32 + srow)      * lda + scol;
    const unsigned short* Ag1 = A  + (size_t)(m0 + wave * 32 + 16 + srow) * lda + scol;
    const unsigned short* Bg0 = Bt + (size_t)(n0 + wave * 32 + srow)      * K + scol;
    const unsigned short* Bg1 = Bt + (size_t)(n0 + wave * 32 + 16 + srow) * K + scol;
    unsigned short* Al0 = As + (wave * 2 + 0) * 512;
    unsigned short* Al1 = As + (wave * 2 + 1) * 512;
    unsigned short* Bl0 = Bs + (wave * 2 + 0) * 512;
    unsigned short* Bl1 = Bs + (wave * 2 + 1) * 512;

    f32x16 acc[2][2] = {};

    for (int k0 = 0; k0 < K; k0 += 32) {
        __syncthreads();
        GLOAD16(Ag0 + k0, Al0);
        GLOAD16(Ag1 + k0, Al1);
        GLOAD16(Bg0 + k0, Bl0);
        GLOAD16(Bg1 + k0, Bl1);
        __syncthreads();

        short8 af[2][2], bf[2][2];
#pragma unroll
        for (int i = 0; i < 2; i++) {
            const int row = wm + i * 32 + l32;
#pragma unroll
            for (int ks = 0; ks < 2; ks++)
                af[i][ks] = *(const short8*)(As + row * 32 + ((ks * 2 + hi) ^ fsw) * 8);
        }
#pragma unroll
        for (int j = 0; j < 2; j++) {
            const int row = wn + j * 32 + l32;
#pragma unroll
            for (int ks = 0; ks < 2; ks++)
                bf[j][ks] = *(const short8*)(Bs + row * 32 + ((ks * 2 + hi) ^ fsw) * 8);
        }
#pragma unroll
        for (int ks = 0; ks < 2; ks++)
#pragma unroll
            for (int i = 0; i < 2; i++)
#pragma unroll
                for (int j = 0; j < 2; j++)
                    acc[i][j] = MFMA32(af[i][ks], bf[j][ks], acc[i][j]);
    }

    if (n0 < 2048) {
        unsigned short* outp = (n0 < 1024) ? Qb : Kb;
        const int cb = (n0 < 1024) ? n0 : n0 - 1024;
        const float QS = (n0 < 1024) ? 0.125f * 1.44269504f : 1.0f;
#pragma unroll
        for (int i = 0; i < 2; i++)
#pragma unroll
            for (int j = 0; j < 2; j++)
#pragma unroll
                for (int r = 0; r < 16; r++) {
                    int row = m0 + wm + i * 32 + (r & 3) + 8 * (r >> 2) + 4 * hi;
                    int col = cb + wn + j * 32 + l32;
                    outp[(size_t)row * 1024 + col] = f2b(acc[i][j][r] * QS);
                }
    } else {
        // V: transpose via LDS bounce. [col][row] layout, word = c*64 + ((row>>1) ^ 4*(c&7)).
        const int b = m0 >> 11;
        const int t0b = m0 & 2047; // within-batch t base (BUG FIX: was m0)
        const int hbase = (n0 - 2048) >> 6;
        __syncthreads(); // all frag reads of last K-step done before smem reuse
#pragma unroll
        for (int p = 0; p < 2; p++) {
            if ((wave & 1) == p) {
#pragma unroll
                for (int i = 0; i < 2; i++)
#pragma unroll
                    for (int j = 0; j < 2; j++) {
                        const int c = j * 32 + l32;
#pragma unroll
                        for (int rg = 0; rg < 4; rg++) {
                            const int rowbase = wm + i * 32 + rg * 8 + 4 * hi;
                            uint2 v;
                            v.x = pack2(acc[i][j][4 * rg + 0], acc[i][j][4 * rg + 1]);
                            v.y = pack2(acc[i][j][4 * rg + 2], acc[i][j][4 * rg + 3]);
                            const int w = c * 64 + ((rowbase >> 1) ^ (4 * (c & 7)));
                            *(uint2*)(smem + 2 * w) = v;
                        }
                    }
            }
            __syncthreads();
#pragma unroll
            for (int it = 0; it < 4; it++) {
                const int id = it * 256 + tid;
                const int c = id >> 4, rg = id & 15;
                const int w = c * 64 + ((rg * 4) ^ (4 * (c & 7)));
                short8 v = *(const short8*)(smem + 2 * w);
                const int h = hbase + p;
                *(short8*)(Vt + ((size_t)((b * 16 + h) * 64 + c)) * 2048 + t0b + rg * 8) = v;
            }
            __syncthreads();
        }
    }
}

// ---------------------------------------------------------------- out-proj GEMM (32x32x16, 64x128 tile)
__global__ __launch_bounds__(256) void gemm_out(const unsigned short* __restrict__ A,
                                                const unsigned short* __restrict__ Bt,
                                                float* __restrict__ C) {
    const int K = 1024, lda = 1024;
    __shared__ unsigned short As[64 * 32];
    __shared__ unsigned short Bs[128 * 32];

    const int tid  = threadIdx.x;
    const int wave = tid >> 6;
    const int lane = tid & 63;
    const int l32  = lane & 31;
    const int hi   = lane >> 5;
    const int m0 = blockIdx.y * 64;
    const int n0 = blockIdx.x * 128;
    const int wm = (wave >> 1) * 32;
    const int wn = (wave & 1) * 64;

    const int srow = lane >> 2;
    const int scol = (((lane & 3) ^ ((lane >> 3) & 3)) * 8);
    const int fsw  = ((l32 >> 1) & 3);

    const unsigned short* Ag  = A  + (size_t)(m0 + wave * 16 + srow) * lda + scol;
    const unsigned short* Bg0 = Bt + (size_t)(n0 + wave * 32 + srow)      * K + scol;
    const unsigned short* Bg1 = Bt + (size_t)(n0 + wave * 32 + 16 + srow) * K + scol;
    unsigned short* Al  = As + wave * 512;
    unsigned short* Bl0 = Bs + (wave * 2 + 0) * 512;
    unsigned short* Bl1 = Bs + (wave * 2 + 1) * 512;

    f32x16 acc[2] = {};

    for (int k0 = 0; k0 < K; k0 += 32) {
        __syncthreads();
        GLOAD16(Ag + k0, Al);
        GLOAD16(Bg0 + k0, Bl0);
        GLOAD16(Bg1 + k0, Bl1);
        __syncthreads();

        short8 af[2], bf[2][2];
        {
            const int row = wm + l32;
#pragma unroll
            for (int ks = 0; ks < 2; ks++)
                af[ks] = *(const short8*)(As + row * 32 + ((ks * 2 + hi) ^ fsw) * 8);
        }
#pragma unroll
        for (int j = 0; j < 2; j++) {
            const int row = wn + j * 32 + l32;
#pragma unroll
            for (int ks = 0; ks < 2; ks++)
                bf[j][ks] = *(const short8*)(Bs + row * 32 + ((ks * 2 + hi) ^ fsw) * 8);
        }
#pragma unroll
        for (int ks = 0; ks < 2; ks++)
#pragma unroll
            for (int j = 0; j < 2; j++)
                acc[j] = MFMA32(af[ks], bf[j][ks], acc[j]);
    }

#pragma unroll
    for (int j = 0; j < 2; j++)
#pragma unroll
        for (int r = 0; r < 16; r++) {
            int row = m0 + wm + (r & 3) + 8 * (r >> 2) + 4 * hi;
            int col = n0 + wn + j * 32 + l32;
            C[(size_t)row * 1024 + col] = acc[j][r];
        }
}

// ---------------------------------------------------------------- flash attention (S^T formulation)
// 64-q blocks, LPT grid, GLOAD16 staging into swizzled panels. Q pre-scaled.
__global__ __launch_bounds__(256) void attention_kernel(const unsigned short* Qb,
                                                        const unsigned short* Kb,
                                                        const unsigned short* Vt,
                                                        unsigned short* attn) {
    const int T = 2048;
    const int bi = blockIdx.x;
    const int qb = 31 - (bi >> 6);
    const int hb = bi & 63;
    const int b = hb >> 4, h = hb & 15;
    const int qb0 = qb * 64;
    const int tid = threadIdx.x, wave = tid >> 6, lane = tid & 63;
    const int l16 = lane & 15, quad = lane >> 4;
    const int qw0 = qb0 + wave * 16;

    const unsigned short* Qp  = Qb + (size_t)b * T * 1024 + h * 64;
    const unsigned short* Kp  = Kb + (size_t)b * T * 1024 + h * 64;
    const unsigned short* Vbh = Vt + ((size_t)(b * 16 + h) * 64) * 2048;

    __shared__ unsigned short Ks[2][64 * 32];
    __shared__ unsigned short Vts[2][64 * 32];
    __shared__ unsigned short Ps[4][16 * 40];
    unsigned short* Psw = Ps[wave];

    short8 qf[2];
#pragma unroll
    for (int kd = 0; kd < 2; kd++)
        qf[kd] = *(const short8*)(Qp + (size_t)(qw0 + l16) * 1024 + kd * 32 + quad * 8);

    f32x4 o[4] = {};
    float l_acc = 0.f;

    const int srow = lane >> 2;
    const int scol = (((lane & 3) ^ ((lane >> 3) & 3)) * 8);
    const int sw8  = ((l16 >> 1) & 3) * 8;
    const size_t ktstep = (wave < 2) ? (size_t)64 * 1024 : (size_t)64;
    const size_t cstep  = (wave < 2) ? (size_t)16 * 1024 : (size_t)16 * T;
    const unsigned short* g0 = (wave < 2)
            ? Kp + (size_t)srow * 1024 + wave * 32 + scol
            : Vbh + (size_t)srow * T + (wave - 2) * 32 + scol;
    unsigned short* l0 = (wave < 2) ? Ks[wave] : Vts[wave - 2];

    for (int kt = 0; kt <= qb; kt++) {
        const int tk0 = kt * 64;
        const unsigned short* g = g0 + (size_t)kt * ktstep;
        __syncthreads();
#pragma unroll
        for (int c = 0; c < 4; c++) GLOAD16(g + c * cstep, l0 + c * 512);
        __syncthreads();

#pragma unroll
        for (int th = 0; th < 2; th++) {
            if (tk0 + th * 32 > qw0 + 15) continue;

            f32x4 s[2];
            bool act[2];
#pragma unroll
            for (int mi = 0; mi < 2; mi++) {
                const int t0 = tk0 + (th * 2 + mi) * 16;
                act[mi] = (t0 <= qw0 + 15);
                s[mi] = (f32x4){0.f, 0.f, 0.f, 0.f};
                if (act[mi]) {
                    const int row = (th * 2 + mi) * 16 + l16;
                    short8 kf0 = *(const short8*)(Ks[0] + row * 32 + (quad * 8 ^ sw8));
                    short8 kf1 = *(const short8*)(Ks[1] + row * 32 + (quad * 8 ^ sw8));
                    s[mi] = MFMA16(kf0, qf[0], s[mi]);
                    s[mi] = MFMA16(kf1, qf[1], s[mi]);
                }
            }
#pragma unroll
            for (int mi = 0; mi < 2; mi++) {
                const int t0 = tk0 + (th * 2 + mi) * 16;
                unsigned pk0 = 0, pk1 = 0;
                if (act[mi]) {
                    const bool full = (t0 + 15) <= qw0;
                    float p[4];
#pragma unroll
                    for (int r = 0; r < 4; r++) {
                        float e = __builtin_amdgcn_exp2f(s[mi][r]);
                        if (!full)
                            e = (t0 + quad * 4 + r <= qw0 + l16) ? e : 0.f;
                        p[r] = e;
                    }
                    l_acc += (p[0] + p[1]) + (p[2] + p[3]);
                    pk0 = pack2(p[0], p[1]);
                    pk1 = pack2(p[2], p[3]);
                }
                uint2 pr; pr.x = pk0; pr.y = pk1;
                *(uint2*)(Psw + l16 * 40 + mi * 16 + quad * 4) = pr;
            }
            short8 pf = *(const short8*)(Psw + l16 * 40 + quad * 8);
#pragma unroll
            for (int dt = 0; dt < 4; dt++) {
                short8 vf = *(const short8*)(Vts[th] + (dt * 16 + l16) * 32 + (quad * 8 ^ sw8));
                o[dt] = MFMA16(vf, pf, o[dt]);
            }
        }
    }

    float l = l_acc;
    l += __shfl_xor(l, 16);
    l += __shfl_xor(l, 32);
    const float rl = 1.f / l;
    const int q = qw0 + l16;
#pragma unroll
    for (int dt = 0; dt < 4; dt++) {
        ushort4 wv;
        wv.x = f2b(o[dt][0] * rl);
        wv.y = f2b(o[dt][1] * rl);
        wv.z = f2b(o[dt][2] * rl);
        wv.w = f2b(o[dt][3] * rl);
        *(ushort4*)(attn + (size_t)(b * T + q) * 1024 + h * 64 + dt * 16 + quad * 4) = wv;
    }
}

// ---------------------------------------------------------------- launch
extern "C" void kernel_launch(void* const* d_in, const int* in_sizes, int n_in,
                              void* d_out, int out_size, void* d_ws, size_t ws_size,
                              hipStream_t stream) {
    const float* x     = (const float*)d_in[0]; // (4,2048,1024)
    const float* w_qkv = (const float*)d_in[1]; // (1024,3072)
    const float* w_out = (const float*)d_in[2]; // (1024,1024)
    float* out = (float*)d_out;

    const int M = 8192, D = 1024, E = 3072;
    const size_t MB = 1048576;

    char* ws = (char*)d_ws;
    unsigned short* xb    = (unsigned short*)ws;              // 16 MB
    unsigned short* wqkvT = (unsigned short*)(ws + 16 * MB);  // 6 MB
    unsigned short* woutT = (unsigned short*)(ws + 22 * MB);  // 2 MB
    unsigned short* Qb    = (unsigned short*)(ws + 24 * MB);  // 16 MB (reused as attn out)
    unsigned short* Kb    = (unsigned short*)(ws + 40 * MB);  // 16 MB
    unsigned short* Vt    = (unsigned short*)(ws + 56 * MB);  // 16 MB -> 72 MB total

    cast4_kernel<<<M * D / 4 / 256, 256, 0, stream>>>(x, xb, M * D / 4);
    transpose_cast_f32<<<dim3(E / 64, D / 64), 256, 0, stream>>>(w_qkv, wqkvT, D, E);
    transpose_cast_f32<<<dim3(D / 64, D / 64), 256, 0, stream>>>(w_out, woutT, D, D);

    gemm_qkv<<<dim3(E / 128, M / 128), 256, 0, stream>>>(xb, wqkvT, Qb, Kb, Vt);

    attention_kernel<<<dim3(2048), 256, 0, stream>>>(Qb, Kb, Vt, Qb);

    gemm_out<<<dim3(D / 128, M / 64), 256, 0, stream>>>(Qb, woutT, out);
}